// Round 20
// baseline (2954.319 us; speedup 1.0000x reference)
//
#include <hip/hip_runtime.h>
#include <hip/hip_bf16.h>

using bf16 = __hip_bfloat16;
typedef __bf16 bf16x8 __attribute__((ext_vector_type(8)));
typedef float f32x4 __attribute__((ext_vector_type(4)));

__device__ __forceinline__ float gelu_exact(float x) {
    return 0.5f * x * (1.0f + erff(x * 0.70710678118654752440f));
}

// async global->LDS, 16B per lane; LDS dest must be wave-uniform (HW adds lane*16)
#define GLD_LDS16(g, l) __builtin_amdgcn_global_load_lds( \
    (__attribute__((address_space(1))) void*)(g),          \
    (__attribute__((address_space(3))) void*)(l), 16, 0, 0)

#define WAITV(n) asm volatile("s_waitcnt vmcnt(" #n ")" ::: "memory")

// C = op(alpha * A @ B^T + bias [+ Res]) ; A[M,K] bf16 (lda), Bt[N,K] bf16 (ldb)
// R16 structure: BK=64 phases, 4 sub-buffers, counted vmcnt, T5 setprio.
// ATOM: split-K over blockIdx.z, atomicAdd into C (C pre-holds residual).
template<int BM,int BN,int WM,int WN,int FM,int FN,int OUT_BF16,int HAS_BIAS,int HAS_RES,int DO_GELU,int HEADS,int MPA,int OCC,int ATOM>
__global__ __launch_bounds__(256, OCC) void gemm_bt(
    const bf16* __restrict__ A, long lda,
    const bf16* __restrict__ Bt, long ldb,
    void* __restrict__ Cv, long ldc,
    const float* __restrict__ bias, const float* __restrict__ Res,
    int K, float alpha,
    const int* __restrict__ mpa_mask, const float* __restrict__ mpa_tok,
    const float* __restrict__ mpa_pos)
{
    static_assert(WM * WN == 4 && BM == WM * FM * 16 && BN == WN * FN * 16, "cfg");
    __shared__ alignas(16) unsigned short As[4][BM * 32];
    __shared__ alignas(16) unsigned short Bs[4][BN * 32];

    if (ATOM) {   // split-K: this block handles K-range [z*K, (z+1)*K)
        A  += (long)blockIdx.z * K;
        Bt += (long)blockIdx.z * K;
    }

    // bijective XCD chunk swizzle (m204) over x,y only
    const int nwg = gridDim.x * gridDim.y;
    const int orig = blockIdx.y * gridDim.x + blockIdx.x;
    const int q = nwg >> 3, r = nwg & 7;
    const int xcd = orig & 7, seq = orig >> 3;
    const int wg = (xcd < r ? xcd * (q + 1) : r * (q + 1) + (xcd - r) * q) + seq;
    const int bn0 = (wg % gridDim.x) * BN;
    const int bm0 = (wg / gridDim.x) * BM;

    const int tid = threadIdx.x;
    const int wave = tid >> 6, lane = tid & 63;
    const int wm = (wave / WN) * (FM * 16);
    const int wn = (wave % WN) * (FN * 16);

    f32x4 acc[FM][FN] = {};

    constexpr int CA = BM / 16, CT = (BM + BN) / 16;
    constexpr int LPT = CT / 4;                       // per-wave loads per K-tile
    static_assert(CT % 4 == 0 && (LPT == 2 || LPT == 3), "stage cfg");
    const int lrow = lane >> 2;
    const int lcol = (((lane & 3) ^ ((lrow >> 1) & 3)) * 8);
    const int nk = K >> 5;

    const int fr = lane & 15;
    const int kg = lane >> 4;
    const int kswz = (kg ^ ((fr >> 1) & 3)) * 8;

    auto stage = [&](int buf, int kt) {
        const int k0 = kt * 32;
        for (int c = wave; c < CT; c += 4) {
            if (c < CA) {
                const bf16* src = A + (long)(bm0 + c * 16 + lrow) * lda + k0 + lcol;
                GLD_LDS16(src, &As[buf][c * 512]);
            } else {
                const int c2 = c - CA;
                const bf16* src = Bt + (long)(bn0 + c2 * 16 + lrow) * ldb + k0 + lcol;
                GLD_LDS16(src, &Bs[buf][c2 * 512]);
            }
        }
    };

    for (int i = 0; i < 4 && i < nk; ++i) stage(i, i);

    for (int t0 = 0; t0 < nk; t0 += 2) {
        const int c = (nk - t0 >= 2) ? 2 : 1;
        const int staged = (t0 + 4 < nk) ? (t0 + 4) : nk;
        const int extra = staged - (t0 + c);             // tiles in flight after wait
        if constexpr (LPT == 2) {
            switch (extra) { case 2: WAITV(4); break; case 1: WAITV(2); break;
                             default: WAITV(0); }
        } else {
            switch (extra) { case 2: WAITV(6); break; case 1: WAITV(3); break;
                             default: WAITV(0); }
        }
        __builtin_amdgcn_s_barrier();
        __builtin_amdgcn_sched_barrier(0);

        #pragma unroll
        for (int u = 0; u < 2; ++u) {
            if (u == 1 && c == 1) break;
            const int cur = (t0 + u) & 3;
            bf16x8 af[FM], bfv[FN];
            #pragma unroll
            for (int m = 0; m < FM; ++m)
                af[m] = *(const bf16x8*)&As[cur][(wm + m * 16 + fr) * 32 + kswz];
            #pragma unroll
            for (int n = 0; n < FN; ++n)
                bfv[n] = *(const bf16x8*)&Bs[cur][(wn + n * 16 + fr) * 32 + kswz];
            __builtin_amdgcn_s_setprio(1);
            #pragma unroll
            for (int m = 0; m < FM; ++m)
                #pragma unroll
                for (int n = 0; n < FN; ++n)
                    acc[m][n] = __builtin_amdgcn_mfma_f32_16x16x32_bf16(af[m], bfv[n], acc[m][n], 0, 0, 0);
            __builtin_amdgcn_s_setprio(0);
        }

        __builtin_amdgcn_sched_barrier(0);
        asm volatile("s_waitcnt lgkmcnt(0)" ::: "memory");   // this wave's ds_reads done
        __builtin_amdgcn_s_barrier();                        // all waves done with these bufs
        if (t0 + 4 < nk) stage((t0 + 4) & 3, t0 + 4);
        if (t0 + 5 < nk) stage((t0 + 5) & 3, t0 + 5);
    }

    // C/D layout: col = lane&15, row = (lane>>4)*4 + j (probe-confirmed)
    const int r0 = (lane >> 4) * 4;
    #pragma unroll
    for (int m = 0; m < FM; ++m) {
        const int rowb = bm0 + wm + m * 16 + r0;
        #pragma unroll
        for (int n = 0; n < FN; ++n) {
            const int col = bn0 + wn + n * 16 + fr;
            #pragma unroll
            for (int j = 0; j < 4; ++j) {
                float v = acc[m][n][j] * alpha;
                if (ATOM) {
                    if (blockIdx.z == 0) v += bias[col];   // bias once
                    atomicAdd(&((float*)Cv)[(long)(rowb + j) * ldc + col], v);
                    continue;
                }
                if (HEADS) {
                    v += (col < 1024) ? bias[col] : ((const float*)Res)[col - 1024];
                    const long idx = (col < 1024)
                        ? (long)(rowb + j) * 1024 + col
                        : 2097152L + (long)(rowb + j) * 1024 + (col - 1024);
                    ((float*)Cv)[idx] = v;
                    continue;
                }
                if (MPA) {
                    const int row = rowb + j;
                    v += bias[col];
                    if (mpa_mask[row] != 0) v = mpa_tok[col];
                    v += mpa_pos[(long)row * ldc + col];
                    ((float*)Cv)[(long)row * ldc + col] = v;
                    continue;
                }
                if (HAS_BIAS) v += bias[col];
                if (HAS_RES)  v += Res[(long)(rowb + j) * ldc + col];
                if (DO_GELU)  v = gelu_exact(v);
                const long idx = (long)(rowb + j) * ldc + col;
                if (OUT_BF16) ((bf16*)Cv)[idx] = __float2bfloat16(v);
                else          ((float*)Cv)[idx] = v;
            }
        }
    }
}

// all GEMMs now cfgB 64x64 (32KB LDS, OCC=4) for max resident blocks
#define GEMM_B(OB,HB,HR,DG) gemm_bt<64,64,2,2,2,2, OB,HB,HR,DG,0,0,4,0>
#define GEMM_H              gemm_bt<64,64,2,2,2,2, 0,1,0,0,1,0,4,0>
#define GEMM_M              gemm_bt<64,64,2,2,2,2, 0,1,0,0,0,1,4,0>
#define GEMM_S              gemm_bt<64,64,2,2,2,2, 0,1,0,0,0,0,4,1>

// ---------------- flash attention: V staged straight from qkv ----------------
template<int HD, int MASKED>
__global__ __launch_bounds__(256) void flash_attn(
    const bf16* __restrict__ qkv, int ldq, int Doff, int nh,
    bf16* __restrict__ Out, int ldo,
    const int* __restrict__ mask, float alpha)
{
    constexpr int KVT = 256, KS = HD + 8, SV = KVT + 8;
    __shared__ unsigned short Ks[KVT * KS];
    __shared__ unsigned short Vs[HD * SV];
    __shared__ unsigned short Pl[4][16 * 40];

    const int bh = blockIdx.y, b = bh / nh, h = bh % nh;
    const int tid = threadIdx.x;
    const int wave = tid >> 6, lane = tid & 63;
    const int q0 = blockIdx.x * 64 + wave * 16;
    const int fr = lane & 15, kg = lane >> 4;

    const bf16* Qb = qkv + ((long)(b * 512 + q0 + fr)) * ldq + h * HD;
    bf16x8 af[HD / 32];
    #pragma unroll
    for (int kc = 0; kc < HD / 32; ++kc)
        af[kc] = *(const bf16x8*)(Qb + kc * 32 + kg * 8);

    const bf16* Kg = qkv + (long)b * 512 * ldq + Doff + h * HD;
    const bf16* Vg = qkv + (long)b * 512 * ldq + 2 * Doff + h * HD;
    const int* mg = mask + (long)b * 512;

    float m[4], l[4];
    f32x4 O[HD / 16] = {};
    #pragma unroll
    for (int j = 0; j < 4; ++j) { m[j] = -INFINITY; l[j] = 0.f; }

    for (int t = 0; t < 512; t += KVT) {
        __syncthreads();
        for (int i = tid; i < KVT * (HD / 8); i += 256) {
            const int rr = i / (HD / 8), c = i % (HD / 8);
            *(bf16x8*)&Ks[rr * KS + c * 8] = *(const bf16x8*)(Kg + (long)(t + rr) * ldq + c * 8);
        }
        for (int i = tid; i < KVT * (HD / 8); i += 256) {
            const int ll = i / (HD / 8), c = i % (HD / 8);
            bf16x8 vv = *(const bf16x8*)(Vg + (long)(t + ll) * ldq + c * 8);
            #pragma unroll
            for (int j = 0; j < 8; ++j) {
                bf16 e = ((const bf16*)&vv)[j];
                Vs[(c * 8 + j) * SV + ll] = *(unsigned short*)&e;
            }
        }
        __syncthreads();

        for (int n0 = 0; n0 < KVT; n0 += 32) {
            f32x4 s[2];
            int msk[2] = {0, 0};
            #pragma unroll
            for (int f = 0; f < 2; ++f) {
                f32x4 a = {};
                __builtin_amdgcn_s_setprio(1);
                #pragma unroll
                for (int kc = 0; kc < HD / 32; ++kc) {
                    bf16x8 kb = *(const bf16x8*)&Ks[(n0 + f * 16 + fr) * KS + kc * 32 + kg * 8];
                    a = __builtin_amdgcn_mfma_f32_16x16x32_bf16(af[kc], kb, a, 0, 0, 0);
                }
                __builtin_amdgcn_s_setprio(0);
                #pragma unroll
                for (int j = 0; j < 4; ++j) a[j] *= alpha;
                s[f] = a;
                if (MASKED) msk[f] = mg[t + n0 + f * 16 + fr];
            }
            float g[4], p0[4], p1[4];
            #pragma unroll
            for (int j = 0; j < 4; ++j) {
                float t4 = fmaxf(s[0][j], s[1][j]);
                t4 = fmaxf(t4, __shfl_xor(t4, 1));
                t4 = fmaxf(t4, __shfl_xor(t4, 2));
                t4 = fmaxf(t4, __shfl_xor(t4, 4));
                t4 = fmaxf(t4, __shfl_xor(t4, 8));
                const float mn = fmaxf(m[j], t4);
                g[j] = __expf(m[j] - mn);
                p0[j] = msk[0] ? 0.f : __expf(s[0][j] - mn);
                p1[j] = msk[1] ? 0.f : __expf(s[1][j] - mn);
                float rs = p0[j] + p1[j];
                rs += __shfl_xor(rs, 1);
                rs += __shfl_xor(rs, 2);
                rs += __shfl_xor(rs, 4);
                rs += __shfl_xor(rs, 8);
                l[j] = l[j] * g[j] + rs;
                m[j] = mn;
            }
            #pragma unroll
            for (int dt = 0; dt < HD / 16; ++dt)
                #pragma unroll
                for (int j = 0; j < 4; ++j) O[dt][j] *= g[j];
            unsigned short* pl = &Pl[wave][0];
            #pragma unroll
            for (int j = 0; j < 4; ++j) {
                bf16 b0 = __float2bfloat16(p0[j]);
                bf16 b1 = __float2bfloat16(p1[j]);
                pl[(kg * 4 + j) * 40 + fr]      = *(unsigned short*)&b0;
                pl[(kg * 4 + j) * 40 + 16 + fr] = *(unsigned short*)&b1;
            }
            __builtin_amdgcn_sched_barrier(0);
            bf16x8 pa = *(const bf16x8*)&pl[fr * 40 + kg * 8];
            __builtin_amdgcn_s_setprio(1);
            #pragma unroll
            for (int dt = 0; dt < HD / 16; ++dt) {
                bf16x8 vb = *(const bf16x8*)&Vs[(dt * 16 + fr) * SV + n0 + kg * 8];
                O[dt] = __builtin_amdgcn_mfma_f32_16x16x32_bf16(pa, vb, O[dt], 0, 0, 0);
            }
            __builtin_amdgcn_s_setprio(0);
        }
    }

    float inv[4];
    #pragma unroll
    for (int j = 0; j < 4; ++j) inv[j] = 1.0f / l[j];
    #pragma unroll
    for (int dt = 0; dt < HD / 16; ++dt)
        #pragma unroll
        for (int j = 0; j < 4; ++j) {
            const long row = (long)b * 512 + q0 + kg * 4 + j;
            Out[row * ldo + h * HD + dt * 16 + fr] = __float2bfloat16(O[dt][j] * inv[j]);
        }
}

// W[K,N] f32 -> Wt[N,Kpad] bf16 (zero-padded K), batched over blockIdx.z
__global__ void transpose_cast_b(const float* __restrict__ in, bf16* __restrict__ out,
                                 int K, int N, int Kpad, long inS, long outS)
{
    __shared__ float tile[32][33];
    in  += (long)blockIdx.z * inS;
    out += (long)blockIdx.z * outS;
    const int n0 = blockIdx.x * 32, k0 = blockIdx.y * 32;
    const int tx = threadIdx.x & 31, ty = threadIdx.x >> 5;
    #pragma unroll
    for (int r = 0; r < 4; ++r) {
        const int k = k0 + ty + r * 8, n = n0 + tx;
        tile[ty + r * 8][tx] = (k < K && n < N) ? in[(long)k * N + n] : 0.0f;
    }
    __syncthreads();
    #pragma unroll
    for (int r = 0; r < 4; ++r) {
        const int n = n0 + ty + r * 8, k = k0 + tx;
        if (n < N && k < Kpad)
            out[(long)n * Kpad + k] = __float2bfloat16(tile[tx][ty + r * 8]);
    }
}

// wave-per-row LayerNorm
template<int Dd, int MASKED>
__global__ __launch_bounds__(256) void ln_wave(
    const float* __restrict__ X, const float* __restrict__ w, const float* __restrict__ b,
    bf16* __restrict__ Y, const int* __restrict__ mask)
{
    const int wave = threadIdx.x >> 6, lane = threadIdx.x & 63;
    const int t = blockIdx.x * 4 + wave;
    const float* x = X + (long)t * Dd;
    constexpr int NE = Dd / 64;
    float v[NE];
    float s = 0.f, s2 = 0.f;
    #pragma unroll
    for (int k = 0; k < NE; ++k) {
        v[k] = x[lane + k * 64];
        s += v[k]; s2 += v[k] * v[k];
    }
    #pragma unroll
    for (int o = 32; o; o >>= 1) { s += __shfl_xor(s, o); s2 += __shfl_xor(s2, o); }
    const float mean = s / Dd;
    const float var = s2 / Dd - mean * mean;
    const float inv = 1.0f / sqrtf(var + 1e-6f);
    const bool zero = MASKED && (mask[t] != 0);
    #pragma unroll
    for (int k = 0; k < NE; ++k) {
        const int c = lane + k * 64;
        const float rr = zero ? 0.0f : ((v[k] - mean) * inv * w[c] + b[c]);
        Y[(long)t * Dd + c] = __float2bfloat16(rr);
    }
}

__global__ void build_feat(const float* __restrict__ coords, const float* __restrict__ depths,
                           bf16* __restrict__ F)
{
    const int t = blockIdx.x * 256 + threadIdx.x;
    if (t >= 2048) return;
    const float* c = coords + t * 4;
    float f[5];
    f[0] = (c[0] + c[1]) * 0.5f / 1024.0f;
    f[1] = (c[2] + c[3]) * 0.5f / 1024.0f;
    f[2] = (c[1] - c[0]) / 1024.0f;
    f[3] = (c[3] - c[2]) / 1024.0f;
    f[4] = depths[t] / 8.0f;
    bf16* o = F + (long)t * 32;
    #pragma unroll
    for (int j = 0; j < 32; ++j)
        o[j] = __float2bfloat16(j < 5 ? f[j] : 0.0f);
}

__global__ void conv_patches(const float* __restrict__ in, bf16* __restrict__ out, int n)
{
    const int i = blockIdx.x * 256 + threadIdx.x;
    if (i < n) out[i] = __float2bfloat16(in[i]);
}

extern "C" void kernel_launch(void* const* d_in, const int* in_sizes, int n_in,
                              void* d_out, int out_size, void* d_ws, size_t ws_size,
                              hipStream_t stream)
{
    (void)in_sizes; (void)n_in; (void)out_size;
    const int D = 768, DD = 512;

    const float* patches    = (const float*)d_in[0];
    const float* coords     = (const float*)d_in[1];
    const float* depths     = (const float*)d_in[2];
    const int*   mask       = (const int*)d_in[3];
    const float* pe_w       = (const float*)d_in[4];
    const float* pe_b       = (const float*)d_in[5];
    const float* pos1_w     = (const float*)d_in[6];
    const float* pos1_b     = (const float*)d_in[7];
    const float* pos2_w     = (const float*)d_in[8];
    const float* pos2_b     = (const float*)d_in[9];
    const float* e_ln1_w    = (const float*)d_in[10];
    const float* e_ln1_b    = (const float*)d_in[11];
    const float* e_qkv_w    = (const float*)d_in[12];
    const float* e_qkv_b    = (const float*)d_in[13];
    const float* e_pr_w     = (const float*)d_in[14];
    const float* e_pr_b     = (const float*)d_in[15];
    const float* e_ln2_w    = (const float*)d_in[16];
    const float* e_ln2_b    = (const float*)d_in[17];
    const float* e_f1_w     = (const float*)d_in[18];
    const float* e_f1_b     = (const float*)d_in[19];
    const float* e_f2_w     = (const float*)d_in[20];
    const float* e_f2_b     = (const float*)d_in[21];
    const float* enorm_w    = (const float*)d_in[22];
    const float* enorm_b    = (const float*)d_in[23];
    const float* de_w       = (const float*)d_in[24];
    const float* de_b       = (const float*)d_in[25];
    const float* mask_token = (const float*)d_in[26];
    const float* dpos1_w    = (const float*)d_in[27];
    const float* dpos1_b    = (const float*)d_in[28];
    const float* dpos2_w    = (const float*)d_in[29];
    const float* dpos2_b    = (const float*)d_in[30];
    const float* d_ln1_w    = (const float*)d_in[31];
    const float* d_ln1_b    = (const float*)d_in[32];
    const float* d_qkv_w    = (const float*)d_in[33];
    const float* d_qkv_b    = (const float*)d_in[34];
    const float* d_pr_w     = (const float*)d_in[35];
    const float* d_pr_b     = (const float*)d_in[36];
    const float* d_ln2_w    = (const float*)d_in[37];
    const float* d_ln2_b    = (const float*)d_in[38];
    const float* d_f1_w     = (const float*)d_in[39];
    const float* d_f1_b     = (const float*)d_in[40];
    const float* d_f2_w     = (const float*)d_in[41];
    const float* d_f2_b     = (const float*)d_in[42];
    const float* dnorm_w    = (const float*)d_in[43];
    const float* dnorm_b    = (const float*)d_in[44];
    const float* hi_w       = (const float*)d_in[45];
    const float* hi_b       = (const float*)d_in[46];
    const float* hn_w       = (const float*)d_in[47];
    const float* hn_b       = (const float*)d_in[48];

    char* p = (char*)d_ws;
    auto alloc = [&](size_t bytes) -> char* {
        char* r = p; p += (bytes + 255) & ~(size_t)255; return r;
    };
    bf16* pe_wt  = (bf16*)alloc(768L * 1024 * 2);
    bf16* pos1t  = (bf16*)alloc(384L * 32 * 2);
    bf16* pos2t  = (bf16*)alloc(768L * 384 * 2);
    bf16* dpos1t = (bf16*)alloc(256L * 32 * 2);
    bf16* dpos2t = (bf16*)alloc(512L * 256 * 2);
    bf16* de_t   = (bf16*)alloc(512L * 768 * 2);
    bf16* hi_t   = (bf16*)alloc(1024L * 512 * 2);
    bf16* hn_t   = (bf16*)alloc(1024L * 512 * 2);
    bf16* wslot  = (bf16*)alloc(3072L * 768 * 2);
    bf16*  feat    = (bf16*)alloc(2048L * 32 * 2);
    bf16*  patchbf = (bf16*)alloc(2048L * 1024 * 2);
    bf16*  poshE   = (bf16*)alloc(2048L * 384 * 2);
    float* posE    = (float*)alloc(2048L * 768 * 4);
    bf16*  poshD   = (bf16*)alloc(2048L * 256 * 2);
    float* posD    = (float*)alloc(2048L * 512 * 4);
    float* xbuf    = (float*)alloc(2048L * 768 * 4);
    bf16*  lnbuf   = (bf16*)alloc(2048L * 768 * 2);
    bf16*  qkvbuf  = (bf16*)alloc(2048L * 2304 * 2);
    bf16*  hid     = (bf16*)alloc(2048L * 3072 * 2);
    bf16*  pin     = (bf16*)alloc(2048L * 768 * 2);
    float* xd      = (float*)alloc(2048L * 512 * 4);

    const size_t bigBytes =
        (12L*2304*768 + 12L*768*768 + 12L*3072*768 + 12L*768*3072 +
          8L*1536*512 +  8L*512*512 +  8L*2048*512 +  8L*512*2048) * 2 + 8 * 256;
    const size_t used = (size_t)(p - (char*)d_ws);
    const bool batched = ws_size >= used + bigBytes;
    bf16 *eqkvt = nullptr, *eprt = nullptr, *ef1t = nullptr, *ef2t = nullptr;
    bf16 *dqkvt = nullptr, *dprt = nullptr, *df1t = nullptr, *df2t = nullptr;
    if (batched) {
        eqkvt = (bf16*)alloc(12L * 2304 * 768 * 2);
        eprt  = (bf16*)alloc(12L * 768 * 768 * 2);
        ef1t  = (bf16*)alloc(12L * 3072 * 768 * 2);
        ef2t  = (bf16*)alloc(12L * 768 * 3072 * 2);
        dqkvt = (bf16*)alloc(8L * 1536 * 512 * 2);
        dprt  = (bf16*)alloc(8L * 512 * 512 * 2);
        df1t  = (bf16*)alloc(8L * 2048 * 512 * 2);
        df2t  = (bf16*)alloc(8L * 512 * 2048 * 2);
    }

    conv_patches<<<8192, 256, 0, stream>>>(patches, patchbf, 2097152);
    build_feat<<<8, 256, 0, stream>>>(coords, depths, feat);

    auto trb = [&](const float* in, bf16* out, int K, int N, int Kpad, int z) {
        dim3 g((N + 31) / 32, (Kpad + 31) / 32, z);
        transpose_cast_b<<<g, 256, 0, stream>>>(in, out, K, N, Kpad, (long)K * N, (long)N * Kpad);
    };
    trb(pe_w,    pe_wt,  1024,  768, 1024, 1);
    trb(pos1_w,  pos1t,     5,  384,   32, 1);
    trb(pos2_w,  pos2t,   384,  768,  384, 1);
    trb(dpos1_w, dpos1t,    5,  256,   32, 1);
    trb(dpos2_w, dpos2t,  256,  512,  256, 1);
    trb(de_w,    de_t,    768,  512,  768, 1);
    trb(hi_w,    hi_t,    512, 1024,  512, 1);
    trb(hn_w,    hn_t,    512, 1024,  512, 1);
    if (batched) {
        trb(e_qkv_w, eqkvt, 768, 2304, 768, 12);
        trb(e_pr_w,  eprt,  768,  768, 768, 12);
        trb(e_f1_w,  ef1t,  768, 3072, 768, 12);
        trb(e_f2_w,  ef2t, 3072,  768, 3072, 12);
        trb(d_qkv_w, dqkvt, 512, 1536, 512, 8);
        trb(d_pr_w,  dprt,  512,  512, 512, 8);
        trb(d_f1_w,  df1t,  512, 2048, 512, 8);
        trb(d_f2_w,  df2t, 2048,  512, 2048, 8);
    }
    auto wsl = [&](const float* src, long off, int K, int N, int Kpad) -> const bf16* {
        dim3 g((N + 31) / 32, (Kpad + 31) / 32, 1);
        transpose_cast_b<<<g, 256, 0, stream>>>(src + off, wslot, K, N, Kpad, 0, 0);
        return wslot;
    };

    // positional MLPs
    GEMM_B(1,1,0,1)<<<dim3(6,32,1),256,0,stream>>>(
        feat, 32, pos1t, 32, poshE, 384, pos1_b, nullptr, 32, 1.0f, nullptr, nullptr, nullptr);
    GEMM_B(0,1,0,0)<<<dim3(12,32,1),256,0,stream>>>(
        poshE, 384, pos2t, 384, posE, 768, pos2_b, nullptr, 384, 1.0f, nullptr, nullptr, nullptr);
    GEMM_B(1,1,0,1)<<<dim3(4,32,1),256,0,stream>>>(
        feat, 32, dpos1t, 32, poshD, 256, dpos1_b, nullptr, 32, 1.0f, nullptr, nullptr, nullptr);
    GEMM_B(0,1,0,0)<<<dim3(8,32,1),256,0,stream>>>(
        poshD, 256, dpos2t, 256, posD, 512, dpos2_b, nullptr, 256, 1.0f, nullptr, nullptr, nullptr);

    // patch embed
    GEMM_B(0,1,1,0)<<<dim3(12,32,1),256,0,stream>>>(
        patchbf, 1024, pe_wt, 1024, xbuf, 768, pe_b, posE, 1024, 1.0f, nullptr, nullptr, nullptr);

    // ---------------- encoder: 12 layers, nh=12, hd=64 ----------------
    for (int i = 0; i < 12; ++i) {
        ln_wave<768,0><<<512,256,0,stream>>>(xbuf, e_ln1_w + i*D, e_ln1_b + i*D, lnbuf, nullptr);
        const bf16* Wq = batched ? eqkvt + (long)i*2304*768
                                 : wsl(e_qkv_w, (long)i*768*2304, 768, 2304, 768);
        GEMM_B(1,1,0,0)<<<dim3(36,32,1),256,0,stream>>>(
            lnbuf, 768, Wq, 768, qkvbuf, 2304, e_qkv_b + i*2304, nullptr, 768, 1.0f, nullptr, nullptr, nullptr);
        flash_attn<64,1><<<dim3(8,48),256,0,stream>>>(
            qkvbuf, 2304, 768, 12, pin, 768, mask, 0.125f);
        const bf16* Wp = batched ? eprt + (long)i*768*768
                                 : wsl(e_pr_w, (long)i*768*768, 768, 768, 768);
        GEMM_S<<<dim3(12,32,2),256,0,stream>>>(
            pin, 768, Wp, 768, xbuf, 768, e_pr_b + i*768, nullptr, 384, 1.0f, nullptr, nullptr, nullptr);
        ln_wave<768,0><<<512,256,0,stream>>>(xbuf, e_ln2_w + i*D, e_ln2_b + i*D, lnbuf, nullptr);
        const bf16* W1 = batched ? ef1t + (long)i*3072*768
                                 : wsl(e_f1_w, (long)i*768*3072, 768, 3072, 768);
        GEMM_B(1,1,0,1)<<<dim3(48,32,1),256,0,stream>>>(
            lnbuf, 768, W1, 768, hid, 3072, e_f1_b + i*3072, nullptr, 768, 1.0f, nullptr, nullptr, nullptr);
        const bf16* W2 = batched ? ef2t + (long)i*768*3072
                                 : wsl(e_f2_w, (long)i*3072*768, 3072, 768, 3072);
        GEMM_S<<<dim3(12,32,3),256,0,stream>>>(
            hid, 3072, W2, 3072, xbuf, 768, e_f2_b + i*768, nullptr, 1024, 1.0f, nullptr, nullptr, nullptr);
    }

    // encoded = where(visible, LN(h), 0); xd = (mask?tok:enc@de+de_b) + posD  (fused)
    ln_wave<768,1><<<512,256,0,stream>>>(xbuf, enorm_w, enorm_b, lnbuf, mask);
    GEMM_M<<<dim3(8,32,1),256,0,stream>>>(
        lnbuf, 768, de_t, 768, xd, 512, de_b, nullptr, 768, 1.0f, mask, mask_token, posD);

    // ---------------- decoder: 8 layers, nh=16, hd=32 ----------------
    for (int i = 0; i < 8; ++i) {
        ln_wave<512,0><<<512,256,0,stream>>>(xd, d_ln1_w + i*DD, d_ln1_b + i*DD, lnbuf, nullptr);
        const bf16* Wq = batched ? dqkvt + (long)i*1536*512
                                 : wsl(d_qkv_w, (long)i*512*1536, 512, 1536, 512);
        GEMM_B(1,1,0,0)<<<dim3(24,32,1),256,0,stream>>>(
            lnbuf, 512, Wq, 512, qkvbuf, 1536, d_qkv_b + i*1536, nullptr, 512, 1.0f, nullptr, nullptr, nullptr);
        flash_attn<32,0><<<dim3(8,64),256,0,stream>>>(
            qkvbuf, 1536, 512, 16, pin, 512, nullptr, 0.17677669529663687f);
        const bf16* Wp = batched ? dprt + (long)i*512*512
                                 : wsl(d_pr_w, (long)i*512*512, 512, 512, 512);
        GEMM_S<<<dim3(8,32,2),256,0,stream>>>(
            pin, 512, Wp, 512, xd, 512, d_pr_b + i*512, nullptr, 256, 1.0f, nullptr, nullptr, nullptr);
        ln_wave<512,0><<<512,256,0,stream>>>(xd, d_ln2_w + i*DD, d_ln2_b + i*DD, lnbuf, nullptr);
        const bf16* W1 = batched ? df1t + (long)i*2048*512
                                 : wsl(d_f1_w, (long)i*512*2048, 512, 2048, 512);
        GEMM_B(1,1,0,1)<<<dim3(32,32,1),256,0,stream>>>(
            lnbuf, 512, W1, 512, hid, 2048, d_f1_b + i*2048, nullptr, 512, 1.0f, nullptr, nullptr, nullptr);
        const bf16* W2 = batched ? df2t + (long)i*512*2048
                                 : wsl(d_f2_w, (long)i*2048*512, 2048, 512, 2048);
        GEMM_S<<<dim3(8,32,4),256,0,stream>>>(
            hid, 2048, W2, 2048, xd, 512, d_f2_b + i*512, nullptr, 512, 1.0f, nullptr, nullptr, nullptr);
    }

    // final LN + single fused head GEMM into d_out (f32, split epilogue)
    ln_wave<512,0><<<512,256,0,stream>>>(xd, dnorm_w, dnorm_b, lnbuf, nullptr);
    GEMM_H<<<dim3(32,32,1),256,0,stream>>>(
        lnbuf, 512, hi_t, 512, (float*)d_out, 1024, hi_b, (const float*)hn_b, 512, 1.0f, nullptr, nullptr, nullptr);
}

// Round 21
// 2951.843 us; speedup vs baseline: 1.0008x; 1.0008x over previous
//
#include <hip/hip_runtime.h>
#include <hip/hip_bf16.h>

using bf16 = __hip_bfloat16;
typedef __bf16 bf16x8 __attribute__((ext_vector_type(8)));
typedef float f32x4 __attribute__((ext_vector_type(4)));

__device__ __forceinline__ float gelu_exact(float x) {
    return 0.5f * x * (1.0f + erff(x * 0.70710678118654752440f));
}

// async global->LDS, 16B per lane; LDS dest must be wave-uniform (HW adds lane*16)
#define GLD_LDS16(g, l) __builtin_amdgcn_global_load_lds( \
    (__attribute__((address_space(1))) void*)(g),          \
    (__attribute__((address_space(3))) void*)(l), 16, 0, 0)

#define WAITV(n) asm volatile("s_waitcnt vmcnt(" #n ")" ::: "memory")

// C = op(alpha * A @ B^T + bias [+ Res]) ; A[M,K] bf16 (lda), Bt[N,K] bf16 (ldb)
// R16 structure: BK=64 phases, 4 sub-buffers, counted vmcnt, T5 setprio.
// ATOM: split-K over blockIdx.z, atomicAdd into C (C pre-holds residual).
template<int BM,int BN,int WM,int WN,int FM,int FN,int OUT_BF16,int HAS_BIAS,int HAS_RES,int DO_GELU,int HEADS,int MPA,int OCC,int ATOM>
__global__ __launch_bounds__(256, OCC) void gemm_bt(
    const bf16* __restrict__ A, long lda,
    const bf16* __restrict__ Bt, long ldb,
    void* __restrict__ Cv, long ldc,
    const float* __restrict__ bias, const float* __restrict__ Res,
    int K, float alpha,
    const int* __restrict__ mpa_mask, const float* __restrict__ mpa_tok,
    const float* __restrict__ mpa_pos)
{
    static_assert(WM * WN == 4 && BM == WM * FM * 16 && BN == WN * FN * 16, "cfg");
    __shared__ alignas(16) unsigned short As[4][BM * 32];
    __shared__ alignas(16) unsigned short Bs[4][BN * 32];

    if (ATOM) {   // split-K: this block handles K-range [z*K, (z+1)*K)
        A  += (long)blockIdx.z * K;
        Bt += (long)blockIdx.z * K;
    }

    // bijective XCD chunk swizzle (m204) over x,y only
    const int nwg = gridDim.x * gridDim.y;
    const int orig = blockIdx.y * gridDim.x + blockIdx.x;
    const int q = nwg >> 3, r = nwg & 7;
    const int xcd = orig & 7, seq = orig >> 3;
    const int wg = (xcd < r ? xcd * (q + 1) : r * (q + 1) + (xcd - r) * q) + seq;
    const int bn0 = (wg % gridDim.x) * BN;
    const int bm0 = (wg / gridDim.x) * BM;

    const int tid = threadIdx.x;
    const int wave = tid >> 6, lane = tid & 63;
    const int wm = (wave / WN) * (FM * 16);
    const int wn = (wave % WN) * (FN * 16);

    f32x4 acc[FM][FN] = {};

    constexpr int CA = BM / 16, CT = (BM + BN) / 16;
    constexpr int LPT = CT / 4;                       // per-wave loads per K-tile
    static_assert(CT % 4 == 0 && (LPT == 2 || LPT == 3), "stage cfg");
    const int lrow = lane >> 2;
    const int lcol = (((lane & 3) ^ ((lrow >> 1) & 3)) * 8);
    const int nk = K >> 5;

    const int fr = lane & 15;
    const int kg = lane >> 4;
    const int kswz = (kg ^ ((fr >> 1) & 3)) * 8;

    auto stage = [&](int buf, int kt) {
        const int k0 = kt * 32;
        for (int c = wave; c < CT; c += 4) {
            if (c < CA) {
                const bf16* src = A + (long)(bm0 + c * 16 + lrow) * lda + k0 + lcol;
                GLD_LDS16(src, &As[buf][c * 512]);
            } else {
                const int c2 = c - CA;
                const bf16* src = Bt + (long)(bn0 + c2 * 16 + lrow) * ldb + k0 + lcol;
                GLD_LDS16(src, &Bs[buf][c2 * 512]);
            }
        }
    };

    for (int i = 0; i < 4 && i < nk; ++i) stage(i, i);

    for (int t0 = 0; t0 < nk; t0 += 2) {
        const int c = (nk - t0 >= 2) ? 2 : 1;
        const int staged = (t0 + 4 < nk) ? (t0 + 4) : nk;
        const int extra = staged - (t0 + c);             // tiles in flight after wait
        if constexpr (LPT == 2) {
            switch (extra) { case 2: WAITV(4); break; case 1: WAITV(2); break;
                             default: WAITV(0); }
        } else {
            switch (extra) { case 2: WAITV(6); break; case 1: WAITV(3); break;
                             default: WAITV(0); }
        }
        __builtin_amdgcn_s_barrier();
        __builtin_amdgcn_sched_barrier(0);

        #pragma unroll
        for (int u = 0; u < 2; ++u) {
            if (u == 1 && c == 1) break;
            const int cur = (t0 + u) & 3;
            bf16x8 af[FM], bfv[FN];
            #pragma unroll
            for (int m = 0; m < FM; ++m)
                af[m] = *(const bf16x8*)&As[cur][(wm + m * 16 + fr) * 32 + kswz];
            #pragma unroll
            for (int n = 0; n < FN; ++n)
                bfv[n] = *(const bf16x8*)&Bs[cur][(wn + n * 16 + fr) * 32 + kswz];
            __builtin_amdgcn_s_setprio(1);
            #pragma unroll
            for (int m = 0; m < FM; ++m)
                #pragma unroll
                for (int n = 0; n < FN; ++n)
                    acc[m][n] = __builtin_amdgcn_mfma_f32_16x16x32_bf16(af[m], bfv[n], acc[m][n], 0, 0, 0);
            __builtin_amdgcn_s_setprio(0);
        }

        __builtin_amdgcn_sched_barrier(0);
        asm volatile("s_waitcnt lgkmcnt(0)" ::: "memory");   // this wave's ds_reads done
        __builtin_amdgcn_s_barrier();                        // all waves done with these bufs
        if (t0 + 4 < nk) stage((t0 + 4) & 3, t0 + 4);
        if (t0 + 5 < nk) stage((t0 + 5) & 3, t0 + 5);
    }

    // C/D layout: col = lane&15, row = (lane>>4)*4 + j (probe-confirmed)
    const int r0 = (lane >> 4) * 4;
    #pragma unroll
    for (int m = 0; m < FM; ++m) {
        const int rowb = bm0 + wm + m * 16 + r0;
        #pragma unroll
        for (int n = 0; n < FN; ++n) {
            const int col = bn0 + wn + n * 16 + fr;
            #pragma unroll
            for (int j = 0; j < 4; ++j) {
                float v = acc[m][n][j] * alpha;
                if (ATOM) {
                    if (blockIdx.z == 0) v += bias[col];   // bias once
                    atomicAdd(&((float*)Cv)[(long)(rowb + j) * ldc + col], v);
                    continue;
                }
                if (HEADS) {
                    v += (col < 1024) ? bias[col] : ((const float*)Res)[col - 1024];
                    const long idx = (col < 1024)
                        ? (long)(rowb + j) * 1024 + col
                        : 2097152L + (long)(rowb + j) * 1024 + (col - 1024);
                    ((float*)Cv)[idx] = v;
                    continue;
                }
                if (MPA) {
                    const int row = rowb + j;
                    v += bias[col];
                    if (mpa_mask[row] != 0) v = mpa_tok[col];
                    v += mpa_pos[(long)row * ldc + col];
                    ((float*)Cv)[(long)row * ldc + col] = v;
                    continue;
                }
                if (HAS_BIAS) v += bias[col];
                if (HAS_RES)  v += Res[(long)(rowb + j) * ldc + col];
                if (DO_GELU)  v = gelu_exact(v);
                const long idx = (long)(rowb + j) * ldc + col;
                if (OUT_BF16) ((bf16*)Cv)[idx] = __float2bfloat16(v);
                else          ((float*)Cv)[idx] = v;
            }
        }
    }
}

// all GEMMs now cfgB 64x64 (32KB LDS, OCC=4) for max resident blocks
#define GEMM_B(OB,HB,HR,DG) gemm_bt<64,64,2,2,2,2, OB,HB,HR,DG,0,0,4,0>
#define GEMM_H              gemm_bt<64,64,2,2,2,2, 0,1,0,0,1,0,4,0>
#define GEMM_M              gemm_bt<64,64,2,2,2,2, 0,1,0,0,0,1,4,0>
#define GEMM_S              gemm_bt<64,64,2,2,2,2, 0,1,0,0,0,0,4,1>

// ---------------- flash attention: V staged straight from qkv ----------------
template<int HD, int MASKED>
__global__ __launch_bounds__(256) void flash_attn(
    const bf16* __restrict__ qkv, int ldq, int Doff, int nh,
    bf16* __restrict__ Out, int ldo,
    const int* __restrict__ mask, float alpha)
{
    constexpr int KVT = 256, KS = HD + 8, SV = KVT + 8;
    __shared__ unsigned short Ks[KVT * KS];
    __shared__ unsigned short Vs[HD * SV];
    __shared__ unsigned short Pl[4][16 * 40];

    const int bh = blockIdx.y, b = bh / nh, h = bh % nh;
    const int tid = threadIdx.x;
    const int wave = tid >> 6, lane = tid & 63;
    const int q0 = blockIdx.x * 64 + wave * 16;
    const int fr = lane & 15, kg = lane >> 4;

    const bf16* Qb = qkv + ((long)(b * 512 + q0 + fr)) * ldq + h * HD;
    bf16x8 af[HD / 32];
    #pragma unroll
    for (int kc = 0; kc < HD / 32; ++kc)
        af[kc] = *(const bf16x8*)(Qb + kc * 32 + kg * 8);

    const bf16* Kg = qkv + (long)b * 512 * ldq + Doff + h * HD;
    const bf16* Vg = qkv + (long)b * 512 * ldq + 2 * Doff + h * HD;
    const int* mg = mask + (long)b * 512;

    float m[4], l[4];
    f32x4 O[HD / 16] = {};
    #pragma unroll
    for (int j = 0; j < 4; ++j) { m[j] = -INFINITY; l[j] = 0.f; }

    for (int t = 0; t < 512; t += KVT) {
        __syncthreads();
        for (int i = tid; i < KVT * (HD / 8); i += 256) {
            const int rr = i / (HD / 8), c = i % (HD / 8);
            *(bf16x8*)&Ks[rr * KS + c * 8] = *(const bf16x8*)(Kg + (long)(t + rr) * ldq + c * 8);
        }
        for (int i = tid; i < KVT * (HD / 8); i += 256) {
            const int ll = i / (HD / 8), c = i % (HD / 8);
            bf16x8 vv = *(const bf16x8*)(Vg + (long)(t + ll) * ldq + c * 8);
            #pragma unroll
            for (int j = 0; j < 8; ++j) {
                bf16 e = ((const bf16*)&vv)[j];
                Vs[(c * 8 + j) * SV + ll] = *(unsigned short*)&e;
            }
        }
        __syncthreads();

        for (int n0 = 0; n0 < KVT; n0 += 32) {
            f32x4 s[2];
            int msk[2] = {0, 0};
            #pragma unroll
            for (int f = 0; f < 2; ++f) {
                f32x4 a = {};
                __builtin_amdgcn_s_setprio(1);
                #pragma unroll
                for (int kc = 0; kc < HD / 32; ++kc) {
                    bf16x8 kb = *(const bf16x8*)&Ks[(n0 + f * 16 + fr) * KS + kc * 32 + kg * 8];
                    a = __builtin_amdgcn_mfma_f32_16x16x32_bf16(af[kc], kb, a, 0, 0, 0);
                }
                __builtin_amdgcn_s_setprio(0);
                #pragma unroll
                for (int j = 0; j < 4; ++j) a[j] *= alpha;
                s[f] = a;
                if (MASKED) msk[f] = mg[t + n0 + f * 16 + fr];
            }
            float g[4], p0[4], p1[4];
            #pragma unroll
            for (int j = 0; j < 4; ++j) {
                float t4 = fmaxf(s[0][j], s[1][j]);
                t4 = fmaxf(t4, __shfl_xor(t4, 1));
                t4 = fmaxf(t4, __shfl_xor(t4, 2));
                t4 = fmaxf(t4, __shfl_xor(t4, 4));
                t4 = fmaxf(t4, __shfl_xor(t4, 8));
                const float mn = fmaxf(m[j], t4);
                g[j] = __expf(m[j] - mn);
                p0[j] = msk[0] ? 0.f : __expf(s[0][j] - mn);
                p1[j] = msk[1] ? 0.f : __expf(s[1][j] - mn);
                float rs = p0[j] + p1[j];
                rs += __shfl_xor(rs, 1);
                rs += __shfl_xor(rs, 2);
                rs += __shfl_xor(rs, 4);
                rs += __shfl_xor(rs, 8);
                l[j] = l[j] * g[j] + rs;
                m[j] = mn;
            }
            #pragma unroll
            for (int dt = 0; dt < HD / 16; ++dt)
                #pragma unroll
                for (int j = 0; j < 4; ++j) O[dt][j] *= g[j];
            unsigned short* pl = &Pl[wave][0];
            #pragma unroll
            for (int j = 0; j < 4; ++j) {
                bf16 b0 = __float2bfloat16(p0[j]);
                bf16 b1 = __float2bfloat16(p1[j]);
                pl[(kg * 4 + j) * 40 + fr]      = *(unsigned short*)&b0;
                pl[(kg * 4 + j) * 40 + 16 + fr] = *(unsigned short*)&b1;
            }
            __builtin_amdgcn_sched_barrier(0);
            bf16x8 pa = *(const bf16x8*)&pl[fr * 40 + kg * 8];
            __builtin_amdgcn_s_setprio(1);
            #pragma unroll
            for (int dt = 0; dt < HD / 16; ++dt) {
                bf16x8 vb = *(const bf16x8*)&Vs[(dt * 16 + fr) * SV + n0 + kg * 8];
                O[dt] = __builtin_amdgcn_mfma_f32_16x16x32_bf16(pa, vb, O[dt], 0, 0, 0);
            }
            __builtin_amdgcn_s_setprio(0);
        }
    }

    float inv[4];
    #pragma unroll
    for (int j = 0; j < 4; ++j) inv[j] = 1.0f / l[j];
    #pragma unroll
    for (int dt = 0; dt < HD / 16; ++dt)
        #pragma unroll
        for (int j = 0; j < 4; ++j) {
            const long row = (long)b * 512 + q0 + kg * 4 + j;
            Out[row * ldo + h * HD + dt * 16 + fr] = __float2bfloat16(O[dt][j] * inv[j]);
        }
}

// W[K,N] f32 -> Wt[N,Kpad] bf16 (zero-padded K), batched over blockIdx.z
__global__ void transpose_cast_b(const float* __restrict__ in, bf16* __restrict__ out,
                                 int K, int N, int Kpad, long inS, long outS)
{
    __shared__ float tile[32][33];
    in  += (long)blockIdx.z * inS;
    out += (long)blockIdx.z * outS;
    const int n0 = blockIdx.x * 32, k0 = blockIdx.y * 32;
    const int tx = threadIdx.x & 31, ty = threadIdx.x >> 5;
    #pragma unroll
    for (int r = 0; r < 4; ++r) {
        const int k = k0 + ty + r * 8, n = n0 + tx;
        tile[ty + r * 8][tx] = (k < K && n < N) ? in[(long)k * N + n] : 0.0f;
    }
    __syncthreads();
    #pragma unroll
    for (int r = 0; r < 4; ++r) {
        const int n = n0 + ty + r * 8, k = k0 + tx;
        if (n < N && k < Kpad)
            out[(long)n * Kpad + k] = __float2bfloat16(tile[tx][ty + r * 8]);
    }
}

// wave-per-row LayerNorm
template<int Dd, int MASKED>
__global__ __launch_bounds__(256) void ln_wave(
    const float* __restrict__ X, const float* __restrict__ w, const float* __restrict__ b,
    bf16* __restrict__ Y, const int* __restrict__ mask)
{
    const int wave = threadIdx.x >> 6, lane = threadIdx.x & 63;
    const int t = blockIdx.x * 4 + wave;
    const float* x = X + (long)t * Dd;
    constexpr int NE = Dd / 64;
    float v[NE];
    float s = 0.f, s2 = 0.f;
    #pragma unroll
    for (int k = 0; k < NE; ++k) {
        v[k] = x[lane + k * 64];
        s += v[k]; s2 += v[k] * v[k];
    }
    #pragma unroll
    for (int o = 32; o; o >>= 1) { s += __shfl_xor(s, o); s2 += __shfl_xor(s2, o); }
    const float mean = s / Dd;
    const float var = s2 / Dd - mean * mean;
    const float inv = 1.0f / sqrtf(var + 1e-6f);
    const bool zero = MASKED && (mask[t] != 0);
    #pragma unroll
    for (int k = 0; k < NE; ++k) {
        const int c = lane + k * 64;
        const float rr = zero ? 0.0f : ((v[k] - mean) * inv * w[c] + b[c]);
        Y[(long)t * Dd + c] = __float2bfloat16(rr);
    }
}

__global__ void build_feat(const float* __restrict__ coords, const float* __restrict__ depths,
                           bf16* __restrict__ F)
{
    const int t = blockIdx.x * 256 + threadIdx.x;
    if (t >= 2048) return;
    const float* c = coords + t * 4;
    float f[5];
    f[0] = (c[0] + c[1]) * 0.5f / 1024.0f;
    f[1] = (c[2] + c[3]) * 0.5f / 1024.0f;
    f[2] = (c[1] - c[0]) / 1024.0f;
    f[3] = (c[3] - c[2]) / 1024.0f;
    f[4] = depths[t] / 8.0f;
    bf16* o = F + (long)t * 32;
    #pragma unroll
    for (int j = 0; j < 32; ++j)
        o[j] = __float2bfloat16(j < 5 ? f[j] : 0.0f);
}

__global__ void conv_patches(const float* __restrict__ in, bf16* __restrict__ out, int n)
{
    const int i = blockIdx.x * 256 + threadIdx.x;
    if (i < n) out[i] = __float2bfloat16(in[i]);
}

extern "C" void kernel_launch(void* const* d_in, const int* in_sizes, int n_in,
                              void* d_out, int out_size, void* d_ws, size_t ws_size,
                              hipStream_t stream)
{
    (void)in_sizes; (void)n_in; (void)out_size;
    const int D = 768, DD = 512;

    const float* patches    = (const float*)d_in[0];
    const float* coords     = (const float*)d_in[1];
    const float* depths     = (const float*)d_in[2];
    const int*   mask       = (const int*)d_in[3];
    const float* pe_w       = (const float*)d_in[4];
    const float* pe_b       = (const float*)d_in[5];
    const float* pos1_w     = (const float*)d_in[6];
    const float* pos1_b     = (const float*)d_in[7];
    const float* pos2_w     = (const float*)d_in[8];
    const float* pos2_b     = (const float*)d_in[9];
    const float* e_ln1_w    = (const float*)d_in[10];
    const float* e_ln1_b    = (const float*)d_in[11];
    const float* e_qkv_w    = (const float*)d_in[12];
    const float* e_qkv_b    = (const float*)d_in[13];
    const float* e_pr_w     = (const float*)d_in[14];
    const float* e_pr_b     = (const float*)d_in[15];
    const float* e_ln2_w    = (const float*)d_in[16];
    const float* e_ln2_b    = (const float*)d_in[17];
    const float* e_f1_w     = (const float*)d_in[18];
    const float* e_f1_b     = (const float*)d_in[19];
    const float* e_f2_w     = (const float*)d_in[20];
    const float* e_f2_b     = (const float*)d_in[21];
    const float* enorm_w    = (const float*)d_in[22];
    const float* enorm_b    = (const float*)d_in[23];
    const float* de_w       = (const float*)d_in[24];
    const float* de_b       = (const float*)d_in[25];
    const float* mask_token = (const float*)d_in[26];
    const float* dpos1_w    = (const float*)d_in[27];
    const float* dpos1_b    = (const float*)d_in[28];
    const float* dpos2_w    = (const float*)d_in[29];
    const float* dpos2_b    = (const float*)d_in[30];
    const float* d_ln1_w    = (const float*)d_in[31];
    const float* d_ln1_b    = (const float*)d_in[32];
    const float* d_qkv_w    = (const float*)d_in[33];
    const float* d_qkv_b    = (const float*)d_in[34];
    const float* d_pr_w     = (const float*)d_in[35];
    const float* d_pr_b     = (const float*)d_in[36];
    const float* d_ln2_w    = (const float*)d_in[37];
    const float* d_ln2_b    = (const float*)d_in[38];
    const float* d_f1_w     = (const float*)d_in[39];
    const float* d_f1_b     = (const float*)d_in[40];
    const float* d_f2_w     = (const float*)d_in[41];
    const float* d_f2_b     = (const float*)d_in[42];
    const float* dnorm_w    = (const float*)d_in[43];
    const float* dnorm_b    = (const float*)d_in[44];
    const float* hi_w       = (const float*)d_in[45];
    const float* hi_b       = (const float*)d_in[46];
    const float* hn_w       = (const float*)d_in[47];
    const float* hn_b       = (const float*)d_in[48];

    char* p = (char*)d_ws;
    auto alloc = [&](size_t bytes) -> char* {
        char* r = p; p += (bytes + 255) & ~(size_t)255; return r;
    };
    bf16* pe_wt  = (bf16*)alloc(768L * 1024 * 2);
    bf16* pos1t  = (bf16*)alloc(384L * 32 * 2);
    bf16* pos2t  = (bf16*)alloc(768L * 384 * 2);
    bf16* dpos1t = (bf16*)alloc(256L * 32 * 2);
    bf16* dpos2t = (bf16*)alloc(512L * 256 * 2);
    bf16* de_t   = (bf16*)alloc(512L * 768 * 2);
    bf16* hi_t   = (bf16*)alloc(1024L * 512 * 2);
    bf16* hn_t   = (bf16*)alloc(1024L * 512 * 2);
    bf16* wslot  = (bf16*)alloc(3072L * 768 * 2);
    bf16*  feat    = (bf16*)alloc(2048L * 32 * 2);
    bf16*  patchbf = (bf16*)alloc(2048L * 1024 * 2);
    bf16*  poshE   = (bf16*)alloc(2048L * 384 * 2);
    float* posE    = (float*)alloc(2048L * 768 * 4);
    bf16*  poshD   = (bf16*)alloc(2048L * 256 * 2);
    float* posD    = (float*)alloc(2048L * 512 * 4);
    float* xbuf    = (float*)alloc(2048L * 768 * 4);
    bf16*  lnbuf   = (bf16*)alloc(2048L * 768 * 2);
    bf16*  qkvbuf  = (bf16*)alloc(2048L * 2304 * 2);
    bf16*  hid     = (bf16*)alloc(2048L * 3072 * 2);
    bf16*  pin     = (bf16*)alloc(2048L * 768 * 2);
    float* xd      = (float*)alloc(2048L * 512 * 4);

    const size_t bigBytes =
        (12L*2304*768 + 12L*768*768 + 12L*3072*768 + 12L*768*3072 +
          8L*1536*512 +  8L*512*512 +  8L*2048*512 +  8L*512*2048) * 2 + 8 * 256;
    const size_t used = (size_t)(p - (char*)d_ws);
    const bool batched = ws_size >= used + bigBytes;
    bf16 *eqkvt = nullptr, *eprt = nullptr, *ef1t = nullptr, *ef2t = nullptr;
    bf16 *dqkvt = nullptr, *dprt = nullptr, *df1t = nullptr, *df2t = nullptr;
    if (batched) {
        eqkvt = (bf16*)alloc(12L * 2304 * 768 * 2);
        eprt  = (bf16*)alloc(12L * 768 * 768 * 2);
        ef1t  = (bf16*)alloc(12L * 3072 * 768 * 2);
        ef2t  = (bf16*)alloc(12L * 768 * 3072 * 2);
        dqkvt = (bf16*)alloc(8L * 1536 * 512 * 2);
        dprt  = (bf16*)alloc(8L * 512 * 512 * 2);
        df1t  = (bf16*)alloc(8L * 2048 * 512 * 2);
        df2t  = (bf16*)alloc(8L * 512 * 2048 * 2);
    }

    conv_patches<<<8192, 256, 0, stream>>>(patches, patchbf, 2097152);
    build_feat<<<8, 256, 0, stream>>>(coords, depths, feat);

    auto trb = [&](const float* in, bf16* out, int K, int N, int Kpad, int z) {
        dim3 g((N + 31) / 32, (Kpad + 31) / 32, z);
        transpose_cast_b<<<g, 256, 0, stream>>>(in, out, K, N, Kpad, (long)K * N, (long)N * Kpad);
    };
    trb(pe_w,    pe_wt,  1024,  768, 1024, 1);
    trb(pos1_w,  pos1t,     5,  384,   32, 1);
    trb(pos2_w,  pos2t,   384,  768,  384, 1);
    trb(dpos1_w, dpos1t,    5,  256,   32, 1);
    trb(dpos2_w, dpos2t,  256,  512,  256, 1);
    trb(de_w,    de_t,    768,  512,  768, 1);
    trb(hi_w,    hi_t,    512, 1024,  512, 1);
    trb(hn_w,    hn_t,    512, 1024,  512, 1);
    if (batched) {
        trb(e_qkv_w, eqkvt, 768, 2304, 768, 12);
        trb(e_pr_w,  eprt,  768,  768, 768, 12);
        trb(e_f1_w,  ef1t,  768, 3072, 768, 12);
        trb(e_f2_w,  ef2t, 3072,  768, 3072, 12);
        trb(d_qkv_w, dqkvt, 512, 1536, 512, 8);
        trb(d_pr_w,  dprt,  512,  512, 512, 8);
        trb(d_f1_w,  df1t,  512, 2048, 512, 8);
        trb(d_f2_w,  df2t, 2048,  512, 2048, 8);
    }
    auto wsl = [&](const float* src, long off, int K, int N, int Kpad) -> const bf16* {
        dim3 g((N + 31) / 32, (Kpad + 31) / 32, 1);
        transpose_cast_b<<<g, 256, 0, stream>>>(src + off, wslot, K, N, Kpad, 0, 0);
        return wslot;
    };

    // positional MLPs
    GEMM_B(1,1,0,1)<<<dim3(6,32,1),256,0,stream>>>(
        feat, 32, pos1t, 32, poshE, 384, pos1_b, nullptr, 32, 1.0f, nullptr, nullptr, nullptr);
    GEMM_B(0,1,0,0)<<<dim3(12,32,1),256,0,stream>>>(
        poshE, 384, pos2t, 384, posE, 768, pos2_b, nullptr, 384, 1.0f, nullptr, nullptr, nullptr);
    GEMM_B(1,1,0,1)<<<dim3(4,32,1),256,0,stream>>>(
        feat, 32, dpos1t, 32, poshD, 256, dpos1_b, nullptr, 32, 1.0f, nullptr, nullptr, nullptr);
    GEMM_B(0,1,0,0)<<<dim3(8,32,1),256,0,stream>>>(
        poshD, 256, dpos2t, 256, posD, 512, dpos2_b, nullptr, 256, 1.0f, nullptr, nullptr, nullptr);

    // patch embed
    GEMM_B(0,1,1,0)<<<dim3(12,32,1),256,0,stream>>>(
        patchbf, 1024, pe_wt, 1024, xbuf, 768, pe_b, posE, 1024, 1.0f, nullptr, nullptr, nullptr);

    // ---------------- encoder: 12 layers, nh=12, hd=64 ----------------
    for (int i = 0; i < 12; ++i) {
        ln_wave<768,0><<<512,256,0,stream>>>(xbuf, e_ln1_w + i*D, e_ln1_b + i*D, lnbuf, nullptr);
        const bf16* Wq = batched ? eqkvt + (long)i*2304*768
                                 : wsl(e_qkv_w, (long)i*768*2304, 768, 2304, 768);
        GEMM_B(1,1,0,0)<<<dim3(36,32,1),256,0,stream>>>(
            lnbuf, 768, Wq, 768, qkvbuf, 2304, e_qkv_b + i*2304, nullptr, 768, 1.0f, nullptr, nullptr, nullptr);
        flash_attn<64,1><<<dim3(8,48),256,0,stream>>>(
            qkvbuf, 2304, 768, 12, pin, 768, mask, 0.125f);
        const bf16* Wp = batched ? eprt + (long)i*768*768
                                 : wsl(e_pr_w, (long)i*768*768, 768, 768, 768);
        GEMM_S<<<dim3(12,32,2),256,0,stream>>>(
            pin, 768, Wp, 768, xbuf, 768, e_pr_b + i*768, nullptr, 384, 1.0f, nullptr, nullptr, nullptr);
        ln_wave<768,0><<<512,256,0,stream>>>(xbuf, e_ln2_w + i*D, e_ln2_b + i*D, lnbuf, nullptr);
        const bf16* W1 = batched ? ef1t + (long)i*3072*768
                                 : wsl(e_f1_w, (long)i*768*3072, 768, 3072, 768);
        GEMM_B(1,1,0,1)<<<dim3(48,32,1),256,0,stream>>>(
            lnbuf, 768, W1, 768, hid, 3072, e_f1_b + i*3072, nullptr, 768, 1.0f, nullptr, nullptr, nullptr);
        const bf16* W2 = batched ? ef2t + (long)i*768*3072
                                 : wsl(e_f2_w, (long)i*3072*768, 3072, 768, 3072);
        GEMM_S<<<dim3(12,32,3),256,0,stream>>>(
            hid, 3072, W2, 3072, xbuf, 768, e_f2_b + i*768, nullptr, 1024, 1.0f, nullptr, nullptr, nullptr);
    }

    // encoded = where(visible, LN(h), 0); xd = (mask?tok:enc@de+de_b) + posD  (fused)
    ln_wave<768,1><<<512,256,0,stream>>>(xbuf, enorm_w, enorm_b, lnbuf, mask);
    GEMM_M<<<dim3(8,32,1),256,0,stream>>>(
        lnbuf, 768, de_t, 768, xd, 512, de_b, nullptr, 768, 1.0f, mask, mask_token, posD);

    // ---------------- decoder: 8 layers, nh=16, hd=32 ----------------
    for (int i = 0; i < 8; ++i) {
        ln_wave<512,0><<<512,256,0,stream>>>(xd, d_ln1_w + i*DD, d_ln1_b + i*DD, lnbuf, nullptr);
        const bf16* Wq = batched ? dqkvt + (long)i*1536*512
                                 : wsl(d_qkv_w, (long)i*512*1536, 512, 1536, 512);
        GEMM_B(1,1,0,0)<<<dim3(24,32,1),256,0,stream>>>(
            lnbuf, 512, Wq, 512, qkvbuf, 1536, d_qkv_b + i*1536, nullptr, 512, 1.0f, nullptr, nullptr, nullptr);
        flash_attn<32,0><<<dim3(8,64),256,0,stream>>>(
            qkvbuf, 1536, 512, 16, pin, 512, nullptr, 0.17677669529663687f);
        const bf16* Wp = batched ? dprt + (long)i*512*512
                                 : wsl(d_pr_w, (long)i*512*512, 512, 512, 512);
        GEMM_S<<<dim3(8,32,2),256,0,stream>>>(
            pin, 512, Wp, 512, xd, 512, d_pr_b + i*512, nullptr, 256, 1.0f, nullptr, nullptr, nullptr);
        ln_wave<512,0><<<512,256,0,stream>>>(xd, d_ln2_w + i*DD, d_ln2_b + i*DD, lnbuf, nullptr);
        const bf16* W1 = batched ? df1t + (long)i*2048*512
                                 : wsl(d_f1_w, (long)i*512*2048, 512, 2048, 512);
        GEMM_B(1,1,0,1)<<<dim3(32,32,1),256,0,stream>>>(
            lnbuf, 512, W1, 512, hid, 2048, d_f1_b + i*2048, nullptr, 512, 1.0f, nullptr, nullptr, nullptr);
        const bf16* W2 = batched ? df2t + (long)i*512*2048
                                 : wsl(d_f2_w, (long)i*2048*512, 2048, 512, 2048);
        GEMM_S<<<dim3(8,32,4),256,0,stream>>>(
            hid, 2048, W2, 2048, xd, 512, d_f2_b + i*512, nullptr, 512, 1.0f, nullptr, nullptr, nullptr);
    }

    // final LN + single fused head GEMM into d_out (f32, split epilogue)
    ln_wave<512,0><<<512,256,0,stream>>>(xd, dnorm_w, dnorm_b, lnbuf, nullptr);
    GEMM_H<<<dim3(32,32,1),256,0,stream>>>(
        lnbuf, 512, hi_t, 512, (float*)d_out, 1024, hi_b, (const float*)hn_b, 512, 1.0f, nullptr, nullptr, nullptr);
}

// Round 22
// 2788.310 us; speedup vs baseline: 1.0595x; 1.0586x over previous
//
#include <hip/hip_runtime.h>
#include <hip/hip_bf16.h>

using bf16 = __hip_bfloat16;
typedef __bf16 bf16x8 __attribute__((ext_vector_type(8)));
typedef float f32x4 __attribute__((ext_vector_type(4)));

__device__ __forceinline__ float gelu_exact(float x) {
    return 0.5f * x * (1.0f + erff(x * 0.70710678118654752440f));
}

// async global->LDS, 16B per lane; LDS dest must be wave-uniform (HW adds lane*16)
#define GLD_LDS16(g, l) __builtin_amdgcn_global_load_lds( \
    (__attribute__((address_space(1))) void*)(g),          \
    (__attribute__((address_space(3))) void*)(l), 16, 0, 0)

#define WAITV(n) asm volatile("s_waitcnt vmcnt(" #n ")" ::: "memory")

// C = op(alpha * A @ B^T + bias [+ Res]) ; A[M,K] bf16 (lda), Bt[N,K] bf16 (ldb)
// R16 structure: BK=64 phases, 4 sub-buffers, counted vmcnt, T5 setprio.
// ATOM: split-K over blockIdx.z, atomicAdd into C (C pre-holds residual).
template<int BM,int BN,int WM,int WN,int FM,int FN,int OUT_BF16,int HAS_BIAS,int HAS_RES,int DO_GELU,int HEADS,int MPA,int OCC,int ATOM>
__global__ __launch_bounds__(256, OCC) void gemm_bt(
    const bf16* __restrict__ A, long lda,
    const bf16* __restrict__ Bt, long ldb,
    void* __restrict__ Cv, long ldc,
    const float* __restrict__ bias, const float* __restrict__ Res,
    int K, float alpha,
    const int* __restrict__ mpa_mask, const float* __restrict__ mpa_tok,
    const float* __restrict__ mpa_pos)
{
    static_assert(WM * WN == 4 && BM == WM * FM * 16 && BN == WN * FN * 16, "cfg");
    __shared__ alignas(16) unsigned short As[4][BM * 32];
    __shared__ alignas(16) unsigned short Bs[4][BN * 32];

    if (ATOM) {   // split-K: this block handles K-range [z*K, (z+1)*K)
        A  += (long)blockIdx.z * K;
        Bt += (long)blockIdx.z * K;
    }

    // bijective XCD chunk swizzle (m204) over x,y only
    const int nwg = gridDim.x * gridDim.y;
    const int orig = blockIdx.y * gridDim.x + blockIdx.x;
    const int q = nwg >> 3, r = nwg & 7;
    const int xcd = orig & 7, seq = orig >> 3;
    const int wg = (xcd < r ? xcd * (q + 1) : r * (q + 1) + (xcd - r) * q) + seq;
    const int bn0 = (wg % gridDim.x) * BN;
    const int bm0 = (wg / gridDim.x) * BM;

    const int tid = threadIdx.x;
    const int wave = tid >> 6, lane = tid & 63;
    const int wm = (wave / WN) * (FM * 16);
    const int wn = (wave % WN) * (FN * 16);

    f32x4 acc[FM][FN] = {};

    constexpr int CA = BM / 16, CT = (BM + BN) / 16;
    constexpr int LPT = CT / 4;                       // per-wave loads per K-tile
    static_assert(CT % 4 == 0 && (LPT == 2 || LPT == 3), "stage cfg");
    const int lrow = lane >> 2;
    const int lcol = (((lane & 3) ^ ((lrow >> 1) & 3)) * 8);
    const int nk = K >> 5;

    const int fr = lane & 15;
    const int kg = lane >> 4;
    const int kswz = (kg ^ ((fr >> 1) & 3)) * 8;

    auto stage = [&](int buf, int kt) {
        const int k0 = kt * 32;
        for (int c = wave; c < CT; c += 4) {
            if (c < CA) {
                const bf16* src = A + (long)(bm0 + c * 16 + lrow) * lda + k0 + lcol;
                GLD_LDS16(src, &As[buf][c * 512]);
            } else {
                const int c2 = c - CA;
                const bf16* src = Bt + (long)(bn0 + c2 * 16 + lrow) * ldb + k0 + lcol;
                GLD_LDS16(src, &Bs[buf][c2 * 512]);
            }
        }
    };

    for (int i = 0; i < 4 && i < nk; ++i) stage(i, i);

    for (int t0 = 0; t0 < nk; t0 += 2) {
        const int c = (nk - t0 >= 2) ? 2 : 1;
        const int staged = (t0 + 4 < nk) ? (t0 + 4) : nk;
        const int extra = staged - (t0 + c);             // tiles in flight after wait
        if constexpr (LPT == 2) {
            switch (extra) { case 2: WAITV(4); break; case 1: WAITV(2); break;
                             default: WAITV(0); }
        } else {
            switch (extra) { case 2: WAITV(6); break; case 1: WAITV(3); break;
                             default: WAITV(0); }
        }
        __builtin_amdgcn_s_barrier();
        __builtin_amdgcn_sched_barrier(0);

        #pragma unroll
        for (int u = 0; u < 2; ++u) {
            if (u == 1 && c == 1) break;
            const int cur = (t0 + u) & 3;
            bf16x8 af[FM], bfv[FN];
            #pragma unroll
            for (int m = 0; m < FM; ++m)
                af[m] = *(const bf16x8*)&As[cur][(wm + m * 16 + fr) * 32 + kswz];
            #pragma unroll
            for (int n = 0; n < FN; ++n)
                bfv[n] = *(const bf16x8*)&Bs[cur][(wn + n * 16 + fr) * 32 + kswz];
            __builtin_amdgcn_s_setprio(1);
            #pragma unroll
            for (int m = 0; m < FM; ++m)
                #pragma unroll
                for (int n = 0; n < FN; ++n)
                    acc[m][n] = __builtin_amdgcn_mfma_f32_16x16x32_bf16(af[m], bfv[n], acc[m][n], 0, 0, 0);
            __builtin_amdgcn_s_setprio(0);
        }

        __builtin_amdgcn_sched_barrier(0);
        asm volatile("s_waitcnt lgkmcnt(0)" ::: "memory");   // this wave's ds_reads done
        __builtin_amdgcn_s_barrier();                        // all waves done with these bufs
        if (t0 + 4 < nk) stage((t0 + 4) & 3, t0 + 4);
        if (t0 + 5 < nk) stage((t0 + 5) & 3, t0 + 5);
    }

    // C/D layout: col = lane&15, row = (lane>>4)*4 + j (probe-confirmed)
    const int r0 = (lane >> 4) * 4;
    #pragma unroll
    for (int m = 0; m < FM; ++m) {
        const int rowb = bm0 + wm + m * 16 + r0;
        #pragma unroll
        for (int n = 0; n < FN; ++n) {
            const int col = bn0 + wn + n * 16 + fr;
            #pragma unroll
            for (int j = 0; j < 4; ++j) {
                float v = acc[m][n][j] * alpha;
                if (ATOM) {
                    if (blockIdx.z == 0) v += bias[col];   // bias once
                    atomicAdd(&((float*)Cv)[(long)(rowb + j) * ldc + col], v);
                    continue;
                }
                if (HEADS) {
                    v += (col < 1024) ? bias[col] : ((const float*)Res)[col - 1024];
                    const long idx = (col < 1024)
                        ? (long)(rowb + j) * 1024 + col
                        : 2097152L + (long)(rowb + j) * 1024 + (col - 1024);
                    ((float*)Cv)[idx] = v;
                    continue;
                }
                if (MPA) {
                    const int row = rowb + j;
                    v += bias[col];
                    if (mpa_mask[row] != 0) v = mpa_tok[col];
                    v += mpa_pos[(long)row * ldc + col];
                    ((float*)Cv)[(long)row * ldc + col] = v;
                    continue;
                }
                if (HAS_BIAS) v += bias[col];
                if (HAS_RES)  v += Res[(long)(rowb + j) * ldc + col];
                if (DO_GELU)  v = gelu_exact(v);
                const long idx = (long)(rowb + j) * ldc + col;
                if (OUT_BF16) ((bf16*)Cv)[idx] = __float2bfloat16(v);
                else          ((float*)Cv)[idx] = v;
            }
        }
    }
}

// cfgA: 64x128 (3/CU) ; cfgB: 64x64 (4/CU) ; GEMM_S: split-K atomic (residual in C)
#define GEMM_A(OB,HB,HR,DG) gemm_bt<64,128,2,2,2,4, OB,HB,HR,DG,0,0,3,0>
#define GEMM_B(OB,HB,HR,DG) gemm_bt<64,64,2,2,2,2, OB,HB,HR,DG,0,0,4,0>
#define GEMM_H              gemm_bt<64,64,2,2,2,2, 0,1,0,0,1,0,4,0>
#define GEMM_M              gemm_bt<64,64,2,2,2,2, 0,1,0,0,0,1,4,0>
#define GEMM_S              gemm_bt<64,64,2,2,2,2, 0,1,0,0,0,0,4,1>

// ---------------- flash attention: V staged straight from qkv ----------------
template<int HD, int MASKED>
__global__ __launch_bounds__(256) void flash_attn(
    const bf16* __restrict__ qkv, int ldq, int Doff, int nh,
    bf16* __restrict__ Out, int ldo,
    const int* __restrict__ mask, float alpha)
{
    constexpr int KVT = 256, KS = HD + 8, SV = KVT + 8;
    __shared__ unsigned short Ks[KVT * KS];
    __shared__ unsigned short Vs[HD * SV];
    __shared__ unsigned short Pl[4][16 * 40];

    const int bh = blockIdx.y, b = bh / nh, h = bh % nh;
    const int tid = threadIdx.x;
    const int wave = tid >> 6, lane = tid & 63;
    const int q0 = blockIdx.x * 64 + wave * 16;
    const int fr = lane & 15, kg = lane >> 4;

    const bf16* Qb = qkv + ((long)(b * 512 + q0 + fr)) * ldq + h * HD;
    bf16x8 af[HD / 32];
    #pragma unroll
    for (int kc = 0; kc < HD / 32; ++kc)
        af[kc] = *(const bf16x8*)(Qb + kc * 32 + kg * 8);

    const bf16* Kg = qkv + (long)b * 512 * ldq + Doff + h * HD;
    const bf16* Vg = qkv + (long)b * 512 * ldq + 2 * Doff + h * HD;
    const int* mg = mask + (long)b * 512;

    float m[4], l[4];
    f32x4 O[HD / 16] = {};
    #pragma unroll
    for (int j = 0; j < 4; ++j) { m[j] = -INFINITY; l[j] = 0.f; }

    for (int t = 0; t < 512; t += KVT) {
        __syncthreads();
        for (int i = tid; i < KVT * (HD / 8); i += 256) {
            const int rr = i / (HD / 8), c = i % (HD / 8);
            *(bf16x8*)&Ks[rr * KS + c * 8] = *(const bf16x8*)(Kg + (long)(t + rr) * ldq + c * 8);
        }
        for (int i = tid; i < KVT * (HD / 8); i += 256) {
            const int ll = i / (HD / 8), c = i % (HD / 8);
            bf16x8 vv = *(const bf16x8*)(Vg + (long)(t + ll) * ldq + c * 8);
            #pragma unroll
            for (int j = 0; j < 8; ++j) {
                bf16 e = ((const bf16*)&vv)[j];
                Vs[(c * 8 + j) * SV + ll] = *(unsigned short*)&e;
            }
        }
        __syncthreads();

        for (int n0 = 0; n0 < KVT; n0 += 32) {
            f32x4 s[2];
            int msk[2] = {0, 0};
            #pragma unroll
            for (int f = 0; f < 2; ++f) {
                f32x4 a = {};
                __builtin_amdgcn_s_setprio(1);
                #pragma unroll
                for (int kc = 0; kc < HD / 32; ++kc) {
                    bf16x8 kb = *(const bf16x8*)&Ks[(n0 + f * 16 + fr) * KS + kc * 32 + kg * 8];
                    a = __builtin_amdgcn_mfma_f32_16x16x32_bf16(af[kc], kb, a, 0, 0, 0);
                }
                __builtin_amdgcn_s_setprio(0);
                #pragma unroll
                for (int j = 0; j < 4; ++j) a[j] *= alpha;
                s[f] = a;
                if (MASKED) msk[f] = mg[t + n0 + f * 16 + fr];
            }
            float g[4], p0[4], p1[4];
            #pragma unroll
            for (int j = 0; j < 4; ++j) {
                float t4 = fmaxf(s[0][j], s[1][j]);
                t4 = fmaxf(t4, __shfl_xor(t4, 1));
                t4 = fmaxf(t4, __shfl_xor(t4, 2));
                t4 = fmaxf(t4, __shfl_xor(t4, 4));
                t4 = fmaxf(t4, __shfl_xor(t4, 8));
                const float mn = fmaxf(m[j], t4);
                g[j] = __expf(m[j] - mn);
                p0[j] = msk[0] ? 0.f : __expf(s[0][j] - mn);
                p1[j] = msk[1] ? 0.f : __expf(s[1][j] - mn);
                float rs = p0[j] + p1[j];
                rs += __shfl_xor(rs, 1);
                rs += __shfl_xor(rs, 2);
                rs += __shfl_xor(rs, 4);
                rs += __shfl_xor(rs, 8);
                l[j] = l[j] * g[j] + rs;
                m[j] = mn;
            }
            #pragma unroll
            for (int dt = 0; dt < HD / 16; ++dt)
                #pragma unroll
                for (int j = 0; j < 4; ++j) O[dt][j] *= g[j];
            unsigned short* pl = &Pl[wave][0];
            #pragma unroll
            for (int j = 0; j < 4; ++j) {
                bf16 b0 = __float2bfloat16(p0[j]);
                bf16 b1 = __float2bfloat16(p1[j]);
                pl[(kg * 4 + j) * 40 + fr]      = *(unsigned short*)&b0;
                pl[(kg * 4 + j) * 40 + 16 + fr] = *(unsigned short*)&b1;
            }
            __builtin_amdgcn_sched_barrier(0);
            bf16x8 pa = *(const bf16x8*)&pl[fr * 40 + kg * 8];
            __builtin_amdgcn_s_setprio(1);
            #pragma unroll
            for (int dt = 0; dt < HD / 16; ++dt) {
                bf16x8 vb = *(const bf16x8*)&Vs[(dt * 16 + fr) * SV + n0 + kg * 8];
                O[dt] = __builtin_amdgcn_mfma_f32_16x16x32_bf16(pa, vb, O[dt], 0, 0, 0);
            }
            __builtin_amdgcn_s_setprio(0);
        }
    }

    float inv[4];
    #pragma unroll
    for (int j = 0; j < 4; ++j) inv[j] = 1.0f / l[j];
    #pragma unroll
    for (int dt = 0; dt < HD / 16; ++dt)
        #pragma unroll
        for (int j = 0; j < 4; ++j) {
            const long row = (long)b * 512 + q0 + kg * 4 + j;
            Out[row * ldo + h * HD + dt * 16 + fr] = __float2bfloat16(O[dt][j] * inv[j]);
        }
}

// W[K,N] f32 -> Wt[N,Kpad] bf16 (zero-padded K), batched over blockIdx.z
__global__ void transpose_cast_b(const float* __restrict__ in, bf16* __restrict__ out,
                                 int K, int N, int Kpad, long inS, long outS)
{
    __shared__ float tile[32][33];
    in  += (long)blockIdx.z * inS;
    out += (long)blockIdx.z * outS;
    const int n0 = blockIdx.x * 32, k0 = blockIdx.y * 32;
    const int tx = threadIdx.x & 31, ty = threadIdx.x >> 5;
    #pragma unroll
    for (int r = 0; r < 4; ++r) {
        const int k = k0 + ty + r * 8, n = n0 + tx;
        tile[ty + r * 8][tx] = (k < K && n < N) ? in[(long)k * N + n] : 0.0f;
    }
    __syncthreads();
    #pragma unroll
    for (int r = 0; r < 4; ++r) {
        const int n = n0 + ty + r * 8, k = k0 + tx;
        if (n < N && k < Kpad)
            out[(long)n * Kpad + k] = __float2bfloat16(tile[tx][ty + r * 8]);
    }
}

// wave-per-row LayerNorm
template<int Dd, int MASKED>
__global__ __launch_bounds__(256) void ln_wave(
    const float* __restrict__ X, const float* __restrict__ w, const float* __restrict__ b,
    bf16* __restrict__ Y, const int* __restrict__ mask)
{
    const int wave = threadIdx.x >> 6, lane = threadIdx.x & 63;
    const int t = blockIdx.x * 4 + wave;
    const float* x = X + (long)t * Dd;
    constexpr int NE = Dd / 64;
    float v[NE];
    float s = 0.f, s2 = 0.f;
    #pragma unroll
    for (int k = 0; k < NE; ++k) {
        v[k] = x[lane + k * 64];
        s += v[k]; s2 += v[k] * v[k];
    }
    #pragma unroll
    for (int o = 32; o; o >>= 1) { s += __shfl_xor(s, o); s2 += __shfl_xor(s2, o); }
    const float mean = s / Dd;
    const float var = s2 / Dd - mean * mean;
    const float inv = 1.0f / sqrtf(var + 1e-6f);
    const bool zero = MASKED && (mask[t] != 0);
    #pragma unroll
    for (int k = 0; k < NE; ++k) {
        const int c = lane + k * 64;
        const float rr = zero ? 0.0f : ((v[k] - mean) * inv * w[c] + b[c]);
        Y[(long)t * Dd + c] = __float2bfloat16(rr);
    }
}

__global__ void build_feat(const float* __restrict__ coords, const float* __restrict__ depths,
                           bf16* __restrict__ F)
{
    const int t = blockIdx.x * 256 + threadIdx.x;
    if (t >= 2048) return;
    const float* c = coords + t * 4;
    float f[5];
    f[0] = (c[0] + c[1]) * 0.5f / 1024.0f;
    f[1] = (c[2] + c[3]) * 0.5f / 1024.0f;
    f[2] = (c[1] - c[0]) / 1024.0f;
    f[3] = (c[3] - c[2]) / 1024.0f;
    f[4] = depths[t] / 8.0f;
    bf16* o = F + (long)t * 32;
    #pragma unroll
    for (int j = 0; j < 32; ++j)
        o[j] = __float2bfloat16(j < 5 ? f[j] : 0.0f);
}

__global__ void conv_patches(const float* __restrict__ in, bf16* __restrict__ out, int n)
{
    const int i = blockIdx.x * 256 + threadIdx.x;
    if (i < n) out[i] = __float2bfloat16(in[i]);
}

extern "C" void kernel_launch(void* const* d_in, const int* in_sizes, int n_in,
                              void* d_out, int out_size, void* d_ws, size_t ws_size,
                              hipStream_t stream)
{
    (void)in_sizes; (void)n_in; (void)out_size;
    const int D = 768, DD = 512;

    const float* patches    = (const float*)d_in[0];
    const float* coords     = (const float*)d_in[1];
    const float* depths     = (const float*)d_in[2];
    const int*   mask       = (const int*)d_in[3];
    const float* pe_w       = (const float*)d_in[4];
    const float* pe_b       = (const float*)d_in[5];
    const float* pos1_w     = (const float*)d_in[6];
    const float* pos1_b     = (const float*)d_in[7];
    const float* pos2_w     = (const float*)d_in[8];
    const float* pos2_b     = (const float*)d_in[9];
    const float* e_ln1_w    = (const float*)d_in[10];
    const float* e_ln1_b    = (const float*)d_in[11];
    const float* e_qkv_w    = (const float*)d_in[12];
    const float* e_qkv_b    = (const float*)d_in[13];
    const float* e_pr_w     = (const float*)d_in[14];
    const float* e_pr_b     = (const float*)d_in[15];
    const float* e_ln2_w    = (const float*)d_in[16];
    const float* e_ln2_b    = (const float*)d_in[17];
    const float* e_f1_w     = (const float*)d_in[18];
    const float* e_f1_b     = (const float*)d_in[19];
    const float* e_f2_w     = (const float*)d_in[20];
    const float* e_f2_b     = (const float*)d_in[21];
    const float* enorm_w    = (const float*)d_in[22];
    const float* enorm_b    = (const float*)d_in[23];
    const float* de_w       = (const float*)d_in[24];
    const float* de_b       = (const float*)d_in[25];
    const float* mask_token = (const float*)d_in[26];
    const float* dpos1_w    = (const float*)d_in[27];
    const float* dpos1_b    = (const float*)d_in[28];
    const float* dpos2_w    = (const float*)d_in[29];
    const float* dpos2_b    = (const float*)d_in[30];
    const float* d_ln1_w    = (const float*)d_in[31];
    const float* d_ln1_b    = (const float*)d_in[32];
    const float* d_qkv_w    = (const float*)d_in[33];
    const float* d_qkv_b    = (const float*)d_in[34];
    const float* d_pr_w     = (const float*)d_in[35];
    const float* d_pr_b     = (const float*)d_in[36];
    const float* d_ln2_w    = (const float*)d_in[37];
    const float* d_ln2_b    = (const float*)d_in[38];
    const float* d_f1_w     = (const float*)d_in[39];
    const float* d_f1_b     = (const float*)d_in[40];
    const float* d_f2_w     = (const float*)d_in[41];
    const float* d_f2_b     = (const float*)d_in[42];
    const float* dnorm_w    = (const float*)d_in[43];
    const float* dnorm_b    = (const float*)d_in[44];
    const float* hi_w       = (const float*)d_in[45];
    const float* hi_b       = (const float*)d_in[46];
    const float* hn_w       = (const float*)d_in[47];
    const float* hn_b       = (const float*)d_in[48];

    char* p = (char*)d_ws;
    auto alloc = [&](size_t bytes) -> char* {
        char* r = p; p += (bytes + 255) & ~(size_t)255; return r;
    };
    bf16* pe_wt  = (bf16*)alloc(768L * 1024 * 2);
    bf16* pos1t  = (bf16*)alloc(384L * 32 * 2);
    bf16* pos2t  = (bf16*)alloc(768L * 384 * 2);
    bf16* dpos1t = (bf16*)alloc(256L * 32 * 2);
    bf16* dpos2t = (bf16*)alloc(512L * 256 * 2);
    bf16* de_t   = (bf16*)alloc(512L * 768 * 2);
    bf16* hi_t   = (bf16*)alloc(1024L * 512 * 2);
    bf16* hn_t   = (bf16*)alloc(1024L * 512 * 2);
    bf16* wslot  = (bf16*)alloc(3072L * 768 * 2);
    bf16*  feat    = (bf16*)alloc(2048L * 32 * 2);
    bf16*  patchbf = (bf16*)alloc(2048L * 1024 * 2);
    bf16*  poshE   = (bf16*)alloc(2048L * 384 * 2);
    float* posE    = (float*)alloc(2048L * 768 * 4);
    bf16*  poshD   = (bf16*)alloc(2048L * 256 * 2);
    float* posD    = (float*)alloc(2048L * 512 * 4);
    float* xbuf    = (float*)alloc(2048L * 768 * 4);
    bf16*  lnbuf   = (bf16*)alloc(2048L * 768 * 2);
    bf16*  qkvbuf  = (bf16*)alloc(2048L * 2304 * 2);
    bf16*  hid     = (bf16*)alloc(2048L * 3072 * 2);
    bf16*  pin     = (bf16*)alloc(2048L * 768 * 2);
    float* xd      = (float*)alloc(2048L * 512 * 4);

    const size_t bigBytes =
        (12L*2304*768 + 12L*768*768 + 12L*3072*768 + 12L*768*3072 +
          8L*1536*512 +  8L*512*512 +  8L*2048*512 +  8L*512*2048) * 2 + 8 * 256;
    const size_t used = (size_t)(p - (char*)d_ws);
    const bool batched = ws_size >= used + bigBytes;
    bf16 *eqkvt = nullptr, *eprt = nullptr, *ef1t = nullptr, *ef2t = nullptr;
    bf16 *dqkvt = nullptr, *dprt = nullptr, *df1t = nullptr, *df2t = nullptr;
    if (batched) {
        eqkvt = (bf16*)alloc(12L * 2304 * 768 * 2);
        eprt  = (bf16*)alloc(12L * 768 * 768 * 2);
        ef1t  = (bf16*)alloc(12L * 3072 * 768 * 2);
        ef2t  = (bf16*)alloc(12L * 768 * 3072 * 2);
        dqkvt = (bf16*)alloc(8L * 1536 * 512 * 2);
        dprt  = (bf16*)alloc(8L * 512 * 512 * 2);
        df1t  = (bf16*)alloc(8L * 2048 * 512 * 2);
        df2t  = (bf16*)alloc(8L * 512 * 2048 * 2);
    }

    conv_patches<<<8192, 256, 0, stream>>>(patches, patchbf, 2097152);
    build_feat<<<8, 256, 0, stream>>>(coords, depths, feat);

    auto trb = [&](const float* in, bf16* out, int K, int N, int Kpad, int z) {
        dim3 g((N + 31) / 32, (Kpad + 31) / 32, z);
        transpose_cast_b<<<g, 256, 0, stream>>>(in, out, K, N, Kpad, (long)K * N, (long)N * Kpad);
    };
    trb(pe_w,    pe_wt,  1024,  768, 1024, 1);
    trb(pos1_w,  pos1t,     5,  384,   32, 1);
    trb(pos2_w,  pos2t,   384,  768,  384, 1);
    trb(dpos1_w, dpos1t,    5,  256,   32, 1);
    trb(dpos2_w, dpos2t,  256,  512,  256, 1);
    trb(de_w,    de_t,    768,  512,  768, 1);
    trb(hi_w,    hi_t,    512, 1024,  512, 1);
    trb(hn_w,    hn_t,    512, 1024,  512, 1);
    if (batched) {
        trb(e_qkv_w, eqkvt, 768, 2304, 768, 12);
        trb(e_pr_w,  eprt,  768,  768, 768, 12);
        trb(e_f1_w,  ef1t,  768, 3072, 768, 12);
        trb(e_f2_w,  ef2t, 3072,  768, 3072, 12);
        trb(d_qkv_w, dqkvt, 512, 1536, 512, 8);
        trb(d_pr_w,  dprt,  512,  512, 512, 8);
        trb(d_f1_w,  df1t,  512, 2048, 512, 8);
        trb(d_f2_w,  df2t, 2048,  512, 2048, 8);
    }
    auto wsl = [&](const float* src, long off, int K, int N, int Kpad) -> const bf16* {
        dim3 g((N + 31) / 32, (Kpad + 31) / 32, 1);
        transpose_cast_b<<<g, 256, 0, stream>>>(src + off, wslot, K, N, Kpad, 0, 0);
        return wslot;
    };

    // positional MLPs
    GEMM_B(1,1,0,1)<<<dim3(6,32,1),256,0,stream>>>(
        feat, 32, pos1t, 32, poshE, 384, pos1_b, nullptr, 32, 1.0f, nullptr, nullptr, nullptr);
    GEMM_B(0,1,0,0)<<<dim3(12,32,1),256,0,stream>>>(
        poshE, 384, pos2t, 384, posE, 768, pos2_b, nullptr, 384, 1.0f, nullptr, nullptr, nullptr);
    GEMM_B(1,1,0,1)<<<dim3(4,32,1),256,0,stream>>>(
        feat, 32, dpos1t, 32, poshD, 256, dpos1_b, nullptr, 32, 1.0f, nullptr, nullptr, nullptr);
    GEMM_B(0,1,0,0)<<<dim3(8,32,1),256,0,stream>>>(
        poshD, 256, dpos2t, 256, posD, 512, dpos2_b, nullptr, 256, 1.0f, nullptr, nullptr, nullptr);

    // patch embed
    GEMM_B(0,1,1,0)<<<dim3(12,32,1),256,0,stream>>>(
        patchbf, 1024, pe_wt, 1024, xbuf, 768, pe_b, posE, 1024, 1.0f, nullptr, nullptr, nullptr);

    // ---------------- encoder: 12 layers, nh=12, hd=64 ----------------
    for (int i = 0; i < 12; ++i) {
        ln_wave<768,0><<<512,256,0,stream>>>(xbuf, e_ln1_w + i*D, e_ln1_b + i*D, lnbuf, nullptr);
        const bf16* Wq = batched ? eqkvt + (long)i*2304*768
                                 : wsl(e_qkv_w, (long)i*768*2304, 768, 2304, 768);
        GEMM_A(1,1,0,0)<<<dim3(18,32,1),256,0,stream>>>(
            lnbuf, 768, Wq, 768, qkvbuf, 2304, e_qkv_b + i*2304, nullptr, 768, 1.0f, nullptr, nullptr, nullptr);
        flash_attn<64,1><<<dim3(8,48),256,0,stream>>>(
            qkvbuf, 2304, 768, 12, pin, 768, mask, 0.125f);
        const bf16* Wp = batched ? eprt + (long)i*768*768
                                 : wsl(e_pr_w, (long)i*768*768, 768, 768, 768);
        GEMM_S<<<dim3(12,32,2),256,0,stream>>>(
            pin, 768, Wp, 768, xbuf, 768, e_pr_b + i*768, nullptr, 384, 1.0f, nullptr, nullptr, nullptr);
        ln_wave<768,0><<<512,256,0,stream>>>(xbuf, e_ln2_w + i*D, e_ln2_b + i*D, lnbuf, nullptr);
        const bf16* W1 = batched ? ef1t + (long)i*3072*768
                                 : wsl(e_f1_w, (long)i*768*3072, 768, 3072, 768);
        GEMM_A(1,1,0,1)<<<dim3(24,32,1),256,0,stream>>>(
            lnbuf, 768, W1, 768, hid, 3072, e_f1_b + i*3072, nullptr, 768, 1.0f, nullptr, nullptr, nullptr);
        const bf16* W2 = batched ? ef2t + (long)i*768*3072
                                 : wsl(e_f2_w, (long)i*3072*768, 3072, 768, 3072);
        GEMM_S<<<dim3(12,32,2),256,0,stream>>>(
            hid, 3072, W2, 3072, xbuf, 768, e_f2_b + i*768, nullptr, 1536, 1.0f, nullptr, nullptr, nullptr);
    }

    // encoded = where(visible, LN(h), 0); xd = (mask?tok:enc@de+de_b) + posD  (fused)
    ln_wave<768,1><<<512,256,0,stream>>>(xbuf, enorm_w, enorm_b, lnbuf, mask);
    GEMM_M<<<dim3(8,32,1),256,0,stream>>>(
        lnbuf, 768, de_t, 768, xd, 512, de_b, nullptr, 768, 1.0f, mask, mask_token, posD);

    // ---------------- decoder: 8 layers, nh=16, hd=32 ----------------
    for (int i = 0; i < 8; ++i) {
        ln_wave<512,0><<<512,256,0,stream>>>(xd, d_ln1_w + i*DD, d_ln1_b + i*DD, lnbuf, nullptr);
        const bf16* Wq = batched ? dqkvt + (long)i*1536*512
                                 : wsl(d_qkv_w, (long)i*512*1536, 512, 1536, 512);
        GEMM_A(1,1,0,0)<<<dim3(12,32,1),256,0,stream>>>(
            lnbuf, 512, Wq, 512, qkvbuf, 1536, d_qkv_b + i*1536, nullptr, 512, 1.0f, nullptr, nullptr, nullptr);
        flash_attn<32,0><<<dim3(8,64),256,0,stream>>>(
            qkvbuf, 1536, 512, 16, pin, 512, nullptr, 0.17677669529663687f);
        const bf16* Wp = batched ? dprt + (long)i*512*512
                                 : wsl(d_pr_w, (long)i*512*512, 512, 512, 512);
        GEMM_S<<<dim3(8,32,2),256,0,stream>>>(
            pin, 512, Wp, 512, xd, 512, d_pr_b + i*512, nullptr, 256, 1.0f, nullptr, nullptr, nullptr);
        ln_wave<512,0><<<512,256,0,stream>>>(xd, d_ln2_w + i*DD, d_ln2_b + i*DD, lnbuf, nullptr);
        const bf16* W1 = batched ? df1t + (long)i*2048*512
                                 : wsl(d_f1_w, (long)i*512*2048, 512, 2048, 512);
        GEMM_A(1,1,0,1)<<<dim3(16,32,1),256,0,stream>>>(
            lnbuf, 512, W1, 512, hid, 2048, d_f1_b + i*2048, nullptr, 512, 1.0f, nullptr, nullptr, nullptr);
        const bf16* W2 = batched ? df2t + (long)i*512*2048
                                 : wsl(d_f2_w, (long)i*2048*512, 2048, 512, 2048);
        GEMM_S<<<dim3(8,32,2),256,0,stream>>>(
            hid, 2048, W2, 2048, xd, 512, d_f2_b + i*512, nullptr, 1024, 1.0f, nullptr, nullptr, nullptr);
    }

    // final LN + single fused head GEMM into d_out (f32, split epilogue)
    ln_wave<512,0><<<512,256,0,stream>>>(xd, dnorm_w, dnorm_b, lnbuf, nullptr);
    GEMM_H<<<dim3(32,32,1),256,0,stream>>>(
        lnbuf, 512, hi_t, 512, (float*)d_out, 1024, hi_b, (const float*)hn_b, 512, 1.0f, nullptr, nullptr, nullptr);
}